// Round 1
// baseline (341.335 us; speedup 1.0000x reference)
//
#include <hip/hip_runtime.h>
#include <hip/hip_bf16.h>

#define NB_TOK 4096
#define NBATCH 4
#define SPLIT  8

// ---------------------------------------------------------------------------
// Kernel A: patch embed (8x8 conv stride 8) + QKV projection, fused.
// grid 256 blocks x 256 thr. Block = one (b, h-row) = 64 tokens; 4 threads
// per token split over output channels (og = tid>>6, wave-uniform).
// ---------------------------------------------------------------------------
__global__ __launch_bounds__(256) void k_embed(
    const float* __restrict__ x,  const float* __restrict__ cw,
    const float* __restrict__ cb, const float* __restrict__ pw,
    const float* __restrict__ pb, float* __restrict__ q,
    float* __restrict__ kk, float* __restrict__ vv)
{
    __shared__ float tok_lds[64][33];
    const int tid  = threadIdx.x;
    const int og   = tid >> 6;     // 0..3, wave-uniform
    const int tl   = tid & 63;     // token-in-row = w
    const int bx   = blockIdx.x;   // 0..255
    const int b    = bx >> 6;
    const int hrow = bx & 63;
    const int n    = hrow * 64 + tl;

    // ---- conv: this thread computes tok[o] for o = og*8 .. og*8+7 ----
    float acc[8];
#pragma unroll
    for (int i = 0; i < 8; ++i) acc[i] = cb[og * 8 + i];

    const float* xb = x + (size_t)b * 3 * 512 * 512;
#pragma unroll
    for (int c = 0; c < 3; ++c) {
        float4 xr[16];
#pragma unroll
        for (int p = 0; p < 8; ++p) {
            const float* row = xb + ((size_t)c * 512 + hrow * 8 + p) * 512 + tl * 8;
            xr[p * 2]     = *(const float4*)row;
            xr[p * 2 + 1] = *(const float4*)(row + 4);
        }
#pragma unroll
        for (int oo = 0; oo < 8; ++oo) {
            const float* wrow = cw + ((size_t)(og * 8 + oo) * 3 + c) * 64;
            float s = 0.f;
#pragma unroll
            for (int j = 0; j < 16; ++j) {
                float4 wv = *(const float4*)(wrow + j * 4);
                s += xr[j].x * wv.x + xr[j].y * wv.y + xr[j].z * wv.z + xr[j].w * wv.w;
            }
            acc[oo] += s;
        }
    }
#pragma unroll
    for (int oo = 0; oo < 8; ++oo) tok_lds[tl][og * 8 + oo] = acc[oo];
    __syncthreads();
    float tok[32];
#pragma unroll
    for (int d = 0; d < 32; ++d) tok[d] = tok_lds[tl][d];

    // ---- projection: this thread computes xs[j] for j = og*24 .. +23 ----
#pragma unroll
    for (int g = 0; g < 6; ++g) {
        int jb = og * 24 + g * 4;
        float r[4];
#pragma unroll
        for (int l = 0; l < 4; ++l) {
            int j = jb + l;
            float s = pb[j];
            const float* prow = pw + j * 32;
#pragma unroll
            for (int d4 = 0; d4 < 8; ++d4) {
                float4 wv = *(const float4*)(prow + d4 * 4);
                s += tok[d4 * 4 + 0] * wv.x + tok[d4 * 4 + 1] * wv.y
                   + tok[d4 * 4 + 2] * wv.z + tok[d4 * 4 + 3] * wv.w;
            }
            r[l] = s;
        }
        float* dst = (jb < 32) ? q : (jb < 64 ? kk : vv);
        *(float4*)(dst + ((size_t)b * NB_TOK + n) * 32 + (jb & 31))
            = make_float4(r[0], r[1], r[2], r[3]);
    }
}

// ---------------------------------------------------------------------------
// Kernel B: inter_part[s] = cos(2*pi*Q K^T) V over m-chunk s (+diag fix).
// grid 512 blocks x 256 thr. One thread = one token (full 32-d acc),
// k/v rows are block-uniform -> scalar loads feed v_fmac_f32 v,s,v.
// ---------------------------------------------------------------------------
__global__ __launch_bounds__(256) void k_attn(
    const float* __restrict__ q, const float* __restrict__ kk,
    const float* __restrict__ vv, float* __restrict__ part)
{
    const int bx = blockIdx.x;          // 0..511
    const int s  = bx & 7;              // m-chunk
    const int b  = bx >> 7;
    const int nb = (bx >> 3) & 15;
    const int n  = nb * 256 + threadIdx.x;

    const float* qrow = q + ((size_t)b * NB_TOK + n) * 32;
    float qr[32];
#pragma unroll
    for (int d4 = 0; d4 < 8; ++d4) {
        float4 t4 = *(const float4*)(qrow + d4 * 4);
        qr[d4 * 4 + 0] = t4.x; qr[d4 * 4 + 1] = t4.y;
        qr[d4 * 4 + 2] = t4.z; qr[d4 * 4 + 3] = t4.w;
    }
    float acc[32];
#pragma unroll
    for (int d = 0; d < 32; ++d) acc[d] = 0.f;

    const float* kbase = kk + (size_t)b * NB_TOK * 32;
    const float* vbase = vv + (size_t)b * NB_TOK * 32;
    const int m0 = s * (NB_TOK / SPLIT);
#pragma unroll 2
    for (int m = m0; m < m0 + NB_TOK / SPLIT; ++m) {
        const float* kr = kbase + (size_t)m * 32;   // uniform -> s_load
        float s0 = 0.f, s1 = 0.f, s2 = 0.f, s3 = 0.f;
#pragma unroll
        for (int d4 = 0; d4 < 8; ++d4) {
            float4 kv = *(const float4*)(kr + d4 * 4);
            s0 += qr[d4 * 4 + 0] * kv.x;
            s1 += qr[d4 * 4 + 1] * kv.y;
            s2 += qr[d4 * 4 + 2] * kv.z;
            s3 += qr[d4 * 4 + 3] * kv.w;
        }
        float lp = (s0 + s1) + (s2 + s3);
        // cos(2*pi*lp): v_cos_f32 takes revolutions; reduce to [0,1) first.
        float cc = __builtin_amdgcn_cosf(lp - floorf(lp));
        const float* vr = vbase + (size_t)m * 32;   // uniform -> s_load
#pragma unroll
        for (int d4 = 0; d4 < 8; ++d4) {
            float4 vq = *(const float4*)(vr + d4 * 4);
            acc[d4 * 4 + 0] += cc * vq.x;
            acc[d4 * 4 + 1] += cc * vq.y;
            acc[d4 * 4 + 2] += cc * vq.z;
            acc[d4 * 4 + 3] += cc * vq.w;
        }
    }

    // diagonal: ref zeroes lp[n][n] -> contribution v_n instead of cos*v_n.
    if ((n >> 9) == s) {
        const float* kr = kbase + (size_t)n * 32;
        float t = 0.f;
#pragma unroll
        for (int d = 0; d < 32; ++d) t += qr[d] * kr[d];
        float cc = __builtin_amdgcn_cosf(t - floorf(t));
        float sc = 1.f - cc;
        const float* vr = vbase + (size_t)n * 32;
#pragma unroll
        for (int d = 0; d < 32; ++d) acc[d] += sc * vr[d];
    }

    float* op = part + ((size_t)(s * NBATCH + b) * NB_TOK + n) * 32;
#pragma unroll
    for (int d4 = 0; d4 < 8; ++d4)
        *(float4*)(op + d4 * 4) = make_float4(acc[d4 * 4 + 0], acc[d4 * 4 + 1],
                                              acc[d4 * 4 + 2], acc[d4 * 4 + 3]);
}

// ---------------------------------------------------------------------------
// Kernel C: sum 8 partials -> inter row, then ConvTranspose 8x8 stride 8.
// grid 256 blocks x 256 thr; 4 threads/token over the 192 outputs.
// ---------------------------------------------------------------------------
__global__ __launch_bounds__(256) void k_deconv(
    const float* __restrict__ part, const float* __restrict__ dw,
    const float* __restrict__ db, float* __restrict__ out)
{
    const int tid  = threadIdx.x;
    const int og   = tid >> 6;    // wave-uniform
    const int tl   = tid & 63;
    const int bx   = blockIdx.x;
    const int b    = bx >> 6;
    const int hrow = bx & 63;
    const int n    = hrow * 64 + tl;

    float ir[32];
#pragma unroll
    for (int d = 0; d < 32; ++d) ir[d] = 0.f;
#pragma unroll
    for (int s = 0; s < SPLIT; ++s) {
        const float* ip = part + ((size_t)(s * NBATCH + b) * NB_TOK + n) * 32;
#pragma unroll
        for (int d4 = 0; d4 < 8; ++d4) {
            float4 t4 = *(const float4*)(ip + d4 * 4);
            ir[d4 * 4 + 0] += t4.x; ir[d4 * 4 + 1] += t4.y;
            ir[d4 * 4 + 2] += t4.z; ir[d4 * 4 + 3] += t4.w;
        }
    }

    float oa[48];
#pragma unroll
    for (int g = 0; g < 12; ++g) {
        int jj = og * 48 + g * 4;
        float bv = db[jj >> 6];
        oa[g * 4 + 0] = bv; oa[g * 4 + 1] = bv;
        oa[g * 4 + 2] = bv; oa[g * 4 + 3] = bv;
    }
#pragma unroll
    for (int i = 0; i < 32; ++i) {
        float iv = ir[i];
#pragma unroll
        for (int g = 0; g < 12; ++g) {
            int jj = og * 48 + g * 4;
            float4 wv = *(const float4*)(dw + ((size_t)i * 3 + (jj >> 6)) * 64 + (jj & 63));
            oa[g * 4 + 0] += iv * wv.x; oa[g * 4 + 1] += iv * wv.y;
            oa[g * 4 + 2] += iv * wv.z; oa[g * 4 + 3] += iv * wv.w;
        }
    }
#pragma unroll
    for (int g = 0; g < 12; ++g) {
        int jj = og * 48 + g * 4;
        int o = jj >> 6, pq = jj & 63, p = pq >> 3, qq = pq & 7;
        *(float4*)(out + (((size_t)b * 3 + o) * 512 + hrow * 8 + p) * 512 + tl * 8 + qq)
            = make_float4(oa[g * 4 + 0], oa[g * 4 + 1], oa[g * 4 + 2], oa[g * 4 + 3]);
    }
}

// ---------------------------------------------------------------------------
extern "C" void kernel_launch(void* const* d_in, const int* in_sizes, int n_in,
                              void* d_out, int out_size, void* d_ws, size_t ws_size,
                              hipStream_t stream)
{
    const float* x  = (const float*)d_in[0];
    const float* cw = (const float*)d_in[1];
    const float* cb = (const float*)d_in[2];
    const float* pw = (const float*)d_in[3];
    const float* pb = (const float*)d_in[4];
    const float* dw = (const float*)d_in[5];
    const float* db = (const float*)d_in[6];
    float* out = (float*)d_out;

    float* ws   = (float*)d_ws;
    const size_t tokf = (size_t)NBATCH * NB_TOK * 32;   // 524288 floats
    float* q    = ws;
    float* kk   = ws + tokf;
    float* vv   = ws + 2 * tokf;
    float* part = ws + 3 * tokf;                        // SPLIT*tokf floats

    hipLaunchKernelGGL(k_embed,  dim3(256), dim3(256), 0, stream,
                       x, cw, cb, pw, pb, q, kk, vv);
    hipLaunchKernelGGL(k_attn,   dim3(512), dim3(256), 0, stream,
                       q, kk, vv, part);
    hipLaunchKernelGGL(k_deconv, dim3(256), dim3(256), 0, stream,
                       part, dw, db, out);
}

// Round 5
// 170.686 us; speedup vs baseline: 1.9998x; 1.9998x over previous
//
#include <hip/hip_runtime.h>
#include <hip/hip_bf16.h>

#define NTOK   4096
#define NBATCH 4
#define SPLIT  8

typedef short bf16x8 __attribute__((ext_vector_type(8)));
typedef float f32x4  __attribute__((ext_vector_type(4)));

static __device__ inline short f2bf(float x) {
    __hip_bfloat16 h = __float2bfloat16(x);
    return __builtin_bit_cast(short, h);
}
static __device__ inline float bf2f(short s) {
    return __bfloat162float(__builtin_bit_cast(__hip_bfloat16, s));
}
static __device__ inline f32x4 mfma16(bf16x8 a, bf16x8 b, f32x4 c) {
    return __builtin_amdgcn_mfma_f32_16x16x32_bf16(a, b, c, 0, 0, 0);
}

// ---------------------------------------------------------------------------
// Kernel A: patch embed + QKV projection. Writes Qh/Ql/Kh/Kl (bf16 hi/lo
// split, row-major [b][n][32]) and V fp32 [b][n][32].
// ---------------------------------------------------------------------------
__global__ __launch_bounds__(256) void k_embed(
    const float* __restrict__ x,  const float* __restrict__ cw,
    const float* __restrict__ cb, const float* __restrict__ pw,
    const float* __restrict__ pb,
    short* __restrict__ qh, short* __restrict__ ql,
    short* __restrict__ kh, short* __restrict__ kl,
    float* __restrict__ vv)
{
    __shared__ float tok_lds[64][33];
    const int tid  = threadIdx.x;
    const int og   = tid >> 6;     // 0..3, wave-uniform
    const int tl   = tid & 63;
    const int bx   = blockIdx.x;
    const int b    = bx >> 6;
    const int hrow = bx & 63;
    const int n    = hrow * 64 + tl;

    float acc[8];
#pragma unroll
    for (int i = 0; i < 8; ++i) acc[i] = cb[og * 8 + i];

    const float* xb = x + (size_t)b * 3 * 512 * 512;
#pragma unroll
    for (int c = 0; c < 3; ++c) {
        float4 xr[16];
#pragma unroll
        for (int p = 0; p < 8; ++p) {
            const float* row = xb + ((size_t)c * 512 + hrow * 8 + p) * 512 + tl * 8;
            xr[p * 2]     = *(const float4*)row;
            xr[p * 2 + 1] = *(const float4*)(row + 4);
        }
#pragma unroll
        for (int oo = 0; oo < 8; ++oo) {
            const float* wrow = cw + ((size_t)(og * 8 + oo) * 3 + c) * 64;
            float s = 0.f;
#pragma unroll
            for (int j = 0; j < 16; ++j) {
                float4 wv = *(const float4*)(wrow + j * 4);
                s += xr[j].x * wv.x + xr[j].y * wv.y + xr[j].z * wv.z + xr[j].w * wv.w;
            }
            acc[oo] += s;
        }
    }
#pragma unroll
    for (int oo = 0; oo < 8; ++oo) tok_lds[tl][og * 8 + oo] = acc[oo];
    __syncthreads();
    float tok[32];
#pragma unroll
    for (int d = 0; d < 32; ++d) tok[d] = tok_lds[tl][d];

    const int toff = (b * NTOK + n) * 32;
#pragma unroll
    for (int g2 = 0; g2 < 6; ++g2) {
        int jb = og * 24 + g2 * 4;
        float r[4];
#pragma unroll
        for (int l2 = 0; l2 < 4; ++l2) {
            int j = jb + l2;
            float s = pb[j];
            const float* prow = pw + j * 32;
#pragma unroll
            for (int d4 = 0; d4 < 8; ++d4) {
                float4 wv = *(const float4*)(prow + d4 * 4);
                s += tok[d4 * 4 + 0] * wv.x + tok[d4 * 4 + 1] * wv.y
                   + tok[d4 * 4 + 2] * wv.z + tok[d4 * 4 + 3] * wv.w;
            }
            r[l2] = s;
        }
        if (jb < 64) {
            short hs[4], ls2[4];
#pragma unroll
            for (int l2 = 0; l2 < 4; ++l2) {
                hs[l2]  = f2bf(r[l2]);
                ls2[l2] = f2bf(r[l2] - bf2f(hs[l2]));
            }
            int off = (jb < 32) ? jb : (jb - 32);
            short* dh = (jb < 32) ? qh : kh;
            short* dl = (jb < 32) ? ql : kl;
            *(short4*)(dh + toff + off) = make_short4(hs[0], hs[1], hs[2], hs[3]);
            *(short4*)(dl + toff + off) = make_short4(ls2[0], ls2[1], ls2[2], ls2[3]);
        } else {
            *(float4*)(vv + toff + (jb - 64)) = make_float4(r[0], r[1], r[2], r[3]);
        }
    }
}

// ---------------------------------------------------------------------------
// Kernel B: build Varr — V rearranged into PV B-fragment lane order, hi/lo
// bf16. Layout: [b][chunk 128][dt 2][hl 2][lane 64][8 bf16].
// Slot (g,j) of lane l holds V[m = c*32 + (j<4 ? 4g+j : 16+4g+j-4)][dt*16 + (l&15)].
// ---------------------------------------------------------------------------
__global__ __launch_bounds__(256) void k_varr(
    const float* __restrict__ vv, short* __restrict__ varr)
{
    const int t = threadIdx.x, l = t & 63, w = t >> 6;
    const int g = l >> 4, r16 = l & 15;
    const int bx = blockIdx.x;          // 128 blocks
    const int b = bx >> 5, cg = bx & 31;
    const int c = cg * 4 + w;           // chunk 0..127
    const float* vb = vv + ((size_t)b * NTOK + c * 32) * 32;
#pragma unroll
    for (int dt = 0; dt < 2; ++dt) {
        bf16x8 hv, lv;
#pragma unroll
        for (int j = 0; j < 8; ++j) {
            int m = (j < 4) ? (4 * g + j) : (16 + 4 * g + (j - 4));
            float xv = vb[m * 32 + dt * 16 + r16];
            short hsj = f2bf(xv);
            hv[j] = hsj;
            lv[j] = f2bf(xv - bf2f(hsj));
        }
        size_t base = ((size_t)b * 128 + c) * 2048 + (size_t)dt * 1024 + (size_t)l * 8;
        *(bf16x8*)(varr + base)       = hv;
        *(bf16x8*)(varr + base + 512) = lv;
    }
}

// ---------------------------------------------------------------------------
// Kernel C: MFMA interference. S' = mfma(K,Q) (3 split products), P = cos,
// PV via Varr (3 split products). No LDS, no barriers. part[s][b][n][32].
// ---------------------------------------------------------------------------
__global__ __launch_bounds__(256, 3) void k_attn(
    const short* __restrict__ qh, const short* __restrict__ ql,
    const short* __restrict__ kh, const short* __restrict__ kl,
    const short* __restrict__ varr, float* __restrict__ part)
{
    const int t = threadIdx.x, l = t & 63, w = t >> 6;
    const int g = l >> 4, r16 = l & 15;
    const int bx = blockIdx.x;                 // 1024 blocks
    const int s = bx & 7, b = (bx >> 3) & 3, nb = bx >> 5;
    const int n0 = nb * 128 + w * 32;
    const int qkbase = b * NTOK * 32;

    bf16x8 qfh[2], qfl[2];
#pragma unroll
    for (int nt = 0; nt < 2; ++nt) {
        int ro = qkbase + (n0 + nt * 16 + r16) * 32 + g * 8;
        qfh[nt] = *(const bf16x8*)(qh + ro);
        qfl[nt] = *(const bf16x8*)(ql + ro);
    }
    f32x4 acc[2][2];
#pragma unroll
    for (int nt = 0; nt < 2; ++nt)
#pragma unroll
        for (int dt = 0; dt < 2; ++dt)
            acc[nt][dt] = (f32x4){0.f, 0.f, 0.f, 0.f};

    for (int ch = 0; ch < 16; ++ch) {
        const int mc = s * 512 + ch * 32;
        bf16x8 kfh[2], kfl[2];
#pragma unroll
        for (int mh = 0; mh < 2; ++mh) {
            int ro = qkbase + (mc + mh * 16 + r16) * 32 + g * 8;
            kfh[mh] = *(const bf16x8*)(kh + ro);
            kfl[mh] = *(const bf16x8*)(kl + ro);
        }
        const short* vbase = varr + ((size_t)(b * 128 + (mc >> 5))) * 2048;
        bf16x8 vf00 = *(const bf16x8*)(vbase + l * 8);
        bf16x8 vf01 = *(const bf16x8*)(vbase + 512 + l * 8);
        bf16x8 vf10 = *(const bf16x8*)(vbase + 1024 + l * 8);
        bf16x8 vf11 = *(const bf16x8*)(vbase + 1536 + l * 8);

        bf16x8 pah[2], pal[2];
#pragma unroll
        for (int nt = 0; nt < 2; ++nt) {
            f32x4 sa = (f32x4){0.f, 0.f, 0.f, 0.f};
            f32x4 sb = (f32x4){0.f, 0.f, 0.f, 0.f};
            sa = mfma16(kfh[0], qfh[nt], sa);
            sa = mfma16(kfh[0], qfl[nt], sa);
            sa = mfma16(kfl[0], qfh[nt], sa);
            sb = mfma16(kfh[1], qfh[nt], sb);
            sb = mfma16(kfh[1], qfl[nt], sb);
            sb = mfma16(kfl[1], qfh[nt], sb);
#pragma unroll
            for (int r = 0; r < 4; ++r) {
                float xa = sa[r];
                float ca = __builtin_amdgcn_cosf(xa - floorf(xa));
                short ha = f2bf(ca);
                pah[nt][r] = ha;
                pal[nt][r] = f2bf(ca - bf2f(ha));
                float xb = sb[r];
                float cb2 = __builtin_amdgcn_cosf(xb - floorf(xb));
                short hb = f2bf(cb2);
                pah[nt][r + 4] = hb;
                pal[nt][r + 4] = f2bf(cb2 - bf2f(hb));
            }
        }
#pragma unroll
        for (int nt = 0; nt < 2; ++nt) {
            acc[nt][0] = mfma16(pah[nt], vf00, acc[nt][0]);
            acc[nt][0] = mfma16(pah[nt], vf01, acc[nt][0]);
            acc[nt][0] = mfma16(pal[nt], vf00, acc[nt][0]);
            acc[nt][1] = mfma16(pah[nt], vf10, acc[nt][1]);
            acc[nt][1] = mfma16(pah[nt], vf11, acc[nt][1]);
            acc[nt][1] = mfma16(pal[nt], vf10, acc[nt][1]);
        }
    }
    float* pbp = part + ((size_t)(s * NBATCH + b) * NTOK) * 32;
#pragma unroll
    for (int nt = 0; nt < 2; ++nt)
#pragma unroll
        for (int dt = 0; dt < 2; ++dt)
#pragma unroll
            for (int r = 0; r < 4; ++r)
                pbp[(n0 + nt * 16 + 4 * g + r) * 32 + dt * 16 + r16] = acc[nt][dt][r];
}

// ---------------------------------------------------------------------------
// Kernel D: sum partials + diagonal fix (+ (1-cos(2pi q.k)) * v_n), then
// ConvTranspose 8x8 stride 8.
// ---------------------------------------------------------------------------
__global__ __launch_bounds__(256) void k_deconv(
    const float* __restrict__ part,
    const short* __restrict__ qh, const short* __restrict__ ql,
    const short* __restrict__ kh, const short* __restrict__ kl,
    const float* __restrict__ vv,
    const float* __restrict__ dw, const float* __restrict__ db,
    float* __restrict__ out)
{
    __shared__ float vt2[32][64];
    __shared__ float dots[64][4];
    __shared__ float coef[64];
    const int tid  = threadIdx.x;
    const int og   = tid >> 6;    // wave index, wave-uniform
    const int tl   = tid & 63;
    const int bx   = blockIdx.x;
    const int b    = bx >> 6;
    const int hrow = bx & 63;
    const int n    = hrow * 64 + tl;
    const int toff = (b * NTOK + n) * 32;

    {   // stage v row (transposed) + per-og dot partial
        const float* vrow = vv + toff + og * 8;
#pragma unroll
        for (int i = 0; i < 8; ++i) vt2[og * 8 + i][tl] = vrow[i];
        float dp = 0.f;
        const short* qhp = qh + toff + og * 8;
        const short* qlp = ql + toff + og * 8;
        const short* khp = kh + toff + og * 8;
        const short* klp = kl + toff + og * 8;
#pragma unroll
        for (int i = 0; i < 8; ++i) {
            float qv = bf2f(qhp[i]) + bf2f(qlp[i]);
            float kv = bf2f(khp[i]) + bf2f(klp[i]);
            dp += qv * kv;
        }
        dots[tl][og] = dp;
    }
    __syncthreads();
    if (og == 0) {
        float sd = (dots[tl][0] + dots[tl][1]) + (dots[tl][2] + dots[tl][3]);
        coef[tl] = 1.f - __builtin_amdgcn_cosf(sd - floorf(sd));
    }
    __syncthreads();

    float ir[32];
#pragma unroll
    for (int d = 0; d < 32; ++d) ir[d] = 0.f;
#pragma unroll
    for (int s = 0; s < SPLIT; ++s) {
        const float* ip = part + ((size_t)(s * NBATCH + b) * NTOK + n) * 32;
#pragma unroll
        for (int d4 = 0; d4 < 8; ++d4) {
            float4 t4 = *(const float4*)(ip + d4 * 4);
            ir[d4 * 4 + 0] += t4.x; ir[d4 * 4 + 1] += t4.y;
            ir[d4 * 4 + 2] += t4.z; ir[d4 * 4 + 3] += t4.w;
        }
    }
    const float cf = coef[tl];
#pragma unroll
    for (int d = 0; d < 32; ++d) ir[d] += cf * vt2[d][tl];

    float oa[48];
#pragma unroll
    for (int g2 = 0; g2 < 12; ++g2) {
        int jj = og * 48 + g2 * 4;
        float bv = db[jj >> 6];
        oa[g2 * 4 + 0] = bv; oa[g2 * 4 + 1] = bv;
        oa[g2 * 4 + 2] = bv; oa[g2 * 4 + 3] = bv;
    }
#pragma unroll
    for (int i = 0; i < 32; ++i) {
        float iv = ir[i];
#pragma unroll
        for (int g2 = 0; g2 < 12; ++g2) {
            int jj = og * 48 + g2 * 4;
            float4 wv = *(const float4*)(dw + ((size_t)i * 3 + (jj >> 6)) * 64 + (jj & 63));
            oa[g2 * 4 + 0] += iv * wv.x; oa[g2 * 4 + 1] += iv * wv.y;
            oa[g2 * 4 + 2] += iv * wv.z; oa[g2 * 4 + 3] += iv * wv.w;
        }
    }
#pragma unroll
    for (int g2 = 0; g2 < 12; ++g2) {
        int jj = og * 48 + g2 * 4;
        int o = jj >> 6, pq = jj & 63, p = pq >> 3, qq = pq & 7;
        *(float4*)(out + (((size_t)b * 3 + o) * 512 + hrow * 8 + p) * 512 + tl * 8 + qq)
            = make_float4(oa[g2 * 4 + 0], oa[g2 * 4 + 1], oa[g2 * 4 + 2], oa[g2 * 4 + 3]);
    }
}

// ---------------------------------------------------------------------------
extern "C" void kernel_launch(void* const* d_in, const int* in_sizes, int n_in,
                              void* d_out, int out_size, void* d_ws, size_t ws_size,
                              hipStream_t stream)
{
    const float* x  = (const float*)d_in[0];
    const float* cw = (const float*)d_in[1];
    const float* cb = (const float*)d_in[2];
    const float* pw = (const float*)d_in[3];
    const float* pb = (const float*)d_in[4];
    const float* dw = (const float*)d_in[5];
    const float* db = (const float*)d_in[6];
    float* out = (float*)d_out;

    char* wsb = (char*)d_ws;
    const size_t MB = 1u << 20;
    short* qh   = (short*)(wsb + 0 * MB);
    short* ql   = (short*)(wsb + 1 * MB);
    short* kh   = (short*)(wsb + 2 * MB);
    short* kl   = (short*)(wsb + 3 * MB);
    float* vv   = (float*)(wsb + 4 * MB);   // 2 MB
    short* varr = (short*)(wsb + 6 * MB);   // 2 MB
    float* part = (float*)(wsb + 8 * MB);   // 16 MB

    hipLaunchKernelGGL(k_embed, dim3(256), dim3(256), 0, stream,
                       x, cw, cb, pw, pb, qh, ql, kh, kl, vv);
    hipLaunchKernelGGL(k_varr, dim3(128), dim3(256), 0, stream, vv, varr);
    hipLaunchKernelGGL(k_attn, dim3(1024), dim3(256), 0, stream,
                       qh, ql, kh, kl, varr, part);
    hipLaunchKernelGGL(k_deconv, dim3(256), dim3(256), 0, stream,
                       part, qh, ql, kh, kl, vv, dw, db, out);
}

// Round 9
// 145.611 us; speedup vs baseline: 2.3442x; 1.1722x over previous
//
#include <hip/hip_runtime.h>
#include <hip/hip_bf16.h>

#define NTOK   4096
#define NBATCH 4
#define SPLIT  8

typedef short bf16x8 __attribute__((ext_vector_type(8)));
typedef float f32x4  __attribute__((ext_vector_type(4)));

static __device__ inline short f2bf(float x) {
    __hip_bfloat16 h = __float2bfloat16(x);
    return __builtin_bit_cast(short, h);
}
static __device__ inline float bf2f(short s) {
    return __bfloat162float(__builtin_bit_cast(__hip_bfloat16, s));
}
static __device__ inline f32x4 mfma16(bf16x8 a, bf16x8 b, f32x4 c) {
    return __builtin_amdgcn_mfma_f32_16x16x32_bf16(a, b, c, 0, 0, 0);
}

// ---------------------------------------------------------------------------
// Kernel A: patch embed + QKV projection + diagonal coefficient.
// Writes Qh/Ql/Kh/Kl (bf16 hi/lo, [b][n][32]), V fp32 [b][n][32],
// coef[b*NTOK+n] = 1 - cos(2*pi * q.k)  (fp32 dot via LDS exchange).
// ---------------------------------------------------------------------------
__global__ __launch_bounds__(256) void k_embed(
    const float* __restrict__ x,  const float* __restrict__ cw,
    const float* __restrict__ cb, const float* __restrict__ pw,
    const float* __restrict__ pb,
    short* __restrict__ qh, short* __restrict__ ql,
    short* __restrict__ kh, short* __restrict__ kl,
    float* __restrict__ vv, float* __restrict__ coef)
{
    __shared__ float tok_lds[64][33];
    __shared__ float qk_lds[64][65];   // [token][q0..31,k0..31], pad->bank-free
    const int tid  = threadIdx.x;
    const int og   = tid >> 6;     // 0..3, wave-uniform
    const int tl   = tid & 63;
    const int bx   = blockIdx.x;
    const int b    = bx >> 6;
    const int hrow = bx & 63;
    const int n    = hrow * 64 + tl;

    float acc[8];
#pragma unroll
    for (int i = 0; i < 8; ++i) acc[i] = cb[og * 8 + i];

    const float* xb = x + (size_t)b * 3 * 512 * 512;
#pragma unroll
    for (int c = 0; c < 3; ++c) {
        float4 xr[16];
#pragma unroll
        for (int p = 0; p < 8; ++p) {
            const float* row = xb + ((size_t)c * 512 + hrow * 8 + p) * 512 + tl * 8;
            xr[p * 2]     = *(const float4*)row;
            xr[p * 2 + 1] = *(const float4*)(row + 4);
        }
#pragma unroll
        for (int oo = 0; oo < 8; ++oo) {
            const float* wrow = cw + ((size_t)(og * 8 + oo) * 3 + c) * 64;
            float s = 0.f;
#pragma unroll
            for (int j = 0; j < 16; ++j) {
                float4 wv = *(const float4*)(wrow + j * 4);
                s += xr[j].x * wv.x + xr[j].y * wv.y + xr[j].z * wv.z + xr[j].w * wv.w;
            }
            acc[oo] += s;
        }
    }
#pragma unroll
    for (int oo = 0; oo < 8; ++oo) tok_lds[tl][og * 8 + oo] = acc[oo];
    __syncthreads();
    float tok[32];
#pragma unroll
    for (int d = 0; d < 32; ++d) tok[d] = tok_lds[tl][d];

    const int toff = (b * NTOK + n) * 32;
#pragma unroll
    for (int g2 = 0; g2 < 6; ++g2) {
        int jb = og * 24 + g2 * 4;
        float r[4];
#pragma unroll
        for (int l2 = 0; l2 < 4; ++l2) {
            int j = jb + l2;
            float s = pb[j];
            const float* prow = pw + j * 32;
#pragma unroll
            for (int d4 = 0; d4 < 8; ++d4) {
                float4 wv = *(const float4*)(prow + d4 * 4);
                s += tok[d4 * 4 + 0] * wv.x + tok[d4 * 4 + 1] * wv.y
                   + tok[d4 * 4 + 2] * wv.z + tok[d4 * 4 + 3] * wv.w;
            }
            r[l2] = s;
        }
        if (jb < 64) {
            // stage fp32 q,k for the diagonal dot
#pragma unroll
            for (int l2 = 0; l2 < 4; ++l2) qk_lds[tl][jb + l2] = r[l2];
            short hs[4], ls2[4];
#pragma unroll
            for (int l2 = 0; l2 < 4; ++l2) {
                hs[l2]  = f2bf(r[l2]);
                ls2[l2] = f2bf(r[l2] - bf2f(hs[l2]));
            }
            int off = (jb < 32) ? jb : (jb - 32);
            short* dh = (jb < 32) ? qh : kh;
            short* dl = (jb < 32) ? ql : kl;
            *(short4*)(dh + toff + off) = make_short4(hs[0], hs[1], hs[2], hs[3]);
            *(short4*)(dl + toff + off) = make_short4(ls2[0], ls2[1], ls2[2], ls2[3]);
        } else {
            *(float4*)(vv + toff + (jb - 64)) = make_float4(r[0], r[1], r[2], r[3]);
        }
    }
    __syncthreads();
    if (og == 0) {
        float dp = 0.f;
#pragma unroll
        for (int d = 0; d < 32; ++d) dp += qk_lds[tl][d] * qk_lds[tl][32 + d];
        coef[b * NTOK + n] = 1.f - __builtin_amdgcn_cosf(dp - floorf(dp));
    }
}

// ---------------------------------------------------------------------------
// Kernel B: build Varr — V in PV B-fragment lane order, hi/lo bf16.
// Layout per (b,chunk): 2048 shorts = [dt 2][hl 2][lane 64][slot 8].
// Coalesced read (float4/thread) -> LDS scatter -> linear bf16x8 write.
// ---------------------------------------------------------------------------
__global__ __launch_bounds__(256) void k_varr(
    const float* __restrict__ vv, short* __restrict__ varr)
{
    __shared__ short lds[2048];
    const int tid = threadIdx.x;
    const int bx  = blockIdx.x;          // 512 blocks: b*128 + chunk
    const int b   = bx >> 7, c = bx & 127;
    const float* vb = vv + ((size_t)b * NTOK + c * 32) * 32;

    const int m  = tid >> 3;             // token in chunk 0..31
    const int d0 = (tid & 7) * 4;        // d base
    float4 v4 = *(const float4*)(vb + tid * 4);
    float vd[4] = {v4.x, v4.y, v4.z, v4.w};
#pragma unroll
    for (int l2 = 0; l2 < 4; ++l2) {
        int d = d0 + l2;
        int dt = d >> 4, r16 = d & 15;
        int g, j;
        if (m < 16) { g = m >> 2; j = m & 3; }
        else        { g = (m - 16) >> 2; j = 4 + ((m - 16) & 3); }
        int lane = g * 16 + r16;
        short hv = f2bf(vd[l2]);
        short lv = f2bf(vd[l2] - bf2f(hv));
        lds[dt * 1024 + 0 * 512 + lane * 8 + j] = hv;
        lds[dt * 1024 + 1 * 512 + lane * 8 + j] = lv;
    }
    __syncthreads();
    *(bf16x8*)(varr + ((size_t)b * 128 + c) * 2048 + tid * 8)
        = *(const bf16x8*)(lds + tid * 8);
}

// ---------------------------------------------------------------------------
// Kernel C: MFMA interference (unchanged). part[s][b][n][32].
// ---------------------------------------------------------------------------
__global__ __launch_bounds__(256, 3) void k_attn(
    const short* __restrict__ qh, const short* __restrict__ ql,
    const short* __restrict__ kh, const short* __restrict__ kl,
    const short* __restrict__ varr, float* __restrict__ part)
{
    const int t = threadIdx.x, l = t & 63, w = t >> 6;
    const int g = l >> 4, r16 = l & 15;
    const int bx = blockIdx.x;                 // 1024 blocks
    const int s = bx & 7, b = (bx >> 3) & 3, nb = bx >> 5;
    const int n0 = nb * 128 + w * 32;
    const int qkbase = b * NTOK * 32;

    bf16x8 qfh[2], qfl[2];
#pragma unroll
    for (int nt = 0; nt < 2; ++nt) {
        int ro = qkbase + (n0 + nt * 16 + r16) * 32 + g * 8;
        qfh[nt] = *(const bf16x8*)(qh + ro);
        qfl[nt] = *(const bf16x8*)(ql + ro);
    }
    f32x4 acc[2][2];
#pragma unroll
    for (int nt = 0; nt < 2; ++nt)
#pragma unroll
        for (int dt = 0; dt < 2; ++dt)
            acc[nt][dt] = (f32x4){0.f, 0.f, 0.f, 0.f};

    for (int ch = 0; ch < 16; ++ch) {
        const int mc = s * 512 + ch * 32;
        bf16x8 kfh[2], kfl[2];
#pragma unroll
        for (int mh = 0; mh < 2; ++mh) {
            int ro = qkbase + (mc + mh * 16 + r16) * 32 + g * 8;
            kfh[mh] = *(const bf16x8*)(kh + ro);
            kfl[mh] = *(const bf16x8*)(kl + ro);
        }
        const short* vbase = varr + ((size_t)(b * 128 + (mc >> 5))) * 2048;
        bf16x8 vf00 = *(const bf16x8*)(vbase + l * 8);
        bf16x8 vf01 = *(const bf16x8*)(vbase + 512 + l * 8);
        bf16x8 vf10 = *(const bf16x8*)(vbase + 1024 + l * 8);
        bf16x8 vf11 = *(const bf16x8*)(vbase + 1536 + l * 8);

        bf16x8 pah[2], pal[2];
#pragma unroll
        for (int nt = 0; nt < 2; ++nt) {
            f32x4 sa = (f32x4){0.f, 0.f, 0.f, 0.f};
            f32x4 sb = (f32x4){0.f, 0.f, 0.f, 0.f};
            sa = mfma16(kfh[0], qfh[nt], sa);
            sa = mfma16(kfh[0], qfl[nt], sa);
            sa = mfma16(kfl[0], qfh[nt], sa);
            sb = mfma16(kfh[1], qfh[nt], sb);
            sb = mfma16(kfh[1], qfl[nt], sb);
            sb = mfma16(kfl[1], qfh[nt], sb);
#pragma unroll
            for (int r = 0; r < 4; ++r) {
                float xa = sa[r];
                float ca = __builtin_amdgcn_cosf(xa - floorf(xa));
                short ha = f2bf(ca);
                pah[nt][r] = ha;
                pal[nt][r] = f2bf(ca - bf2f(ha));
                float xb = sb[r];
                float cb2 = __builtin_amdgcn_cosf(xb - floorf(xb));
                short hb = f2bf(cb2);
                pah[nt][r + 4] = hb;
                pal[nt][r + 4] = f2bf(cb2 - bf2f(hb));
            }
        }
#pragma unroll
        for (int nt = 0; nt < 2; ++nt) {
            acc[nt][0] = mfma16(pah[nt], vf00, acc[nt][0]);
            acc[nt][0] = mfma16(pah[nt], vf01, acc[nt][0]);
            acc[nt][0] = mfma16(pal[nt], vf00, acc[nt][0]);
            acc[nt][1] = mfma16(pah[nt], vf10, acc[nt][1]);
            acc[nt][1] = mfma16(pah[nt], vf11, acc[nt][1]);
            acc[nt][1] = mfma16(pal[nt], vf10, acc[nt][1]);
        }
    }
    float* pbp = part + ((size_t)(s * NBATCH + b) * NTOK) * 32;
#pragma unroll
    for (int nt = 0; nt < 2; ++nt)
#pragma unroll
        for (int dt = 0; dt < 2; ++dt)
#pragma unroll
            for (int r = 0; r < 4; ++r)
                pbp[(n0 + nt * 16 + 4 * g + r) * 32 + dt * 16 + r16] = acc[nt][dt][r];
}

// ---------------------------------------------------------------------------
// Kernel R: inter = sum_s part[s] + coef * v. Pure streaming, one
// float4/thread. 512 blocks x 256 thr.
// ---------------------------------------------------------------------------
__global__ __launch_bounds__(256) void k_reduce(
    const float* __restrict__ part, const float* __restrict__ vv,
    const float* __restrict__ coef, float* __restrict__ inter)
{
    const int idx = blockIdx.x * 256 + threadIdx.x;   // 0..131071
    const int g = idx >> 3, d4 = idx & 7;
    const float* p0 = part + (size_t)g * 32 + d4 * 4;
    float4 s = make_float4(0.f, 0.f, 0.f, 0.f);
#pragma unroll
    for (int sp = 0; sp < SPLIT; ++sp) {
        float4 t = *(const float4*)(p0 + (size_t)sp * (NBATCH * NTOK * 32));
        s.x += t.x; s.y += t.y; s.z += t.z; s.w += t.w;
    }
    const float cf = coef[g];
    float4 v4 = *(const float4*)(vv + (size_t)g * 32 + d4 * 4);
    s.x += cf * v4.x; s.y += cf * v4.y; s.z += cf * v4.z; s.w += cf * v4.w;
    *(float4*)(inter + (size_t)g * 32 + d4 * 4) = s;
}

// ---------------------------------------------------------------------------
// Kernel D: ConvTranspose 8x8 stride 8 from inter. 256 blocks x 512 thr.
// Wave owns an h-row x 3 (o,p) output rows; lane = token (w). dw reads are
// wave-uniform -> scalar-cache; stores are dense 2KB/wave-instruction-pair.
// ---------------------------------------------------------------------------
__global__ __launch_bounds__(512) void k_deconv(
    const float* __restrict__ inter, const float* __restrict__ dw,
    const float* __restrict__ db, float* __restrict__ out)
{
    const int tid  = threadIdx.x;
    const int wv   = tid >> 6;     // 0..7, wave-uniform
    const int lane = tid & 63;     // token w
    const int bx   = blockIdx.x;
    const int b    = bx >> 6;
    const int hrow = bx & 63;
    const int n    = hrow * 64 + lane;

    float ir[32];
    const float* ip = inter + ((size_t)(b * NTOK + n)) * 32;
#pragma unroll
    for (int d4 = 0; d4 < 8; ++d4) {
        float4 t4 = *(const float4*)(ip + d4 * 4);
        ir[d4 * 4 + 0] = t4.x; ir[d4 * 4 + 1] = t4.y;
        ir[d4 * 4 + 2] = t4.z; ir[d4 * 4 + 3] = t4.w;
    }
#pragma unroll
    for (int rr = 0; rr < 3; ++rr) {
        const int rho = wv * 3 + rr;      // 0..23, wave-uniform
        const int o = rho >> 3, p = rho & 7;
        const float bv = db[o];
        float a8[8];
#pragma unroll
        for (int q = 0; q < 8; ++q) a8[q] = bv;
        const float* wbase = dw + o * 64 + p * 8;
#pragma unroll
        for (int i = 0; i < 32; ++i) {
            float4 w0 = *(const float4*)(wbase + (size_t)i * 192);
            float4 w1 = *(const float4*)(wbase + (size_t)i * 192 + 4);
            const float iv = ir[i];
            a8[0] += iv * w0.x; a8[1] += iv * w0.y;
            a8[2] += iv * w0.z; a8[3] += iv * w0.w;
            a8[4] += iv * w1.x; a8[5] += iv * w1.y;
            a8[6] += iv * w1.z; a8[7] += iv * w1.w;
        }
        float* op = out + (((size_t)(b * 3 + o) * 512) + hrow * 8 + p) * 512 + lane * 8;
        *(float4*)op       = make_float4(a8[0], a8[1], a8[2], a8[3]);
        *(float4*)(op + 4) = make_float4(a8[4], a8[5], a8[6], a8[7]);
    }
}

// ---------------------------------------------------------------------------
extern "C" void kernel_launch(void* const* d_in, const int* in_sizes, int n_in,
                              void* d_out, int out_size, void* d_ws, size_t ws_size,
                              hipStream_t stream)
{
    const float* x  = (const float*)d_in[0];
    const float* cw = (const float*)d_in[1];
    const float* cb = (const float*)d_in[2];
    const float* pw = (const float*)d_in[3];
    const float* pb = (const float*)d_in[4];
    const float* dw = (const float*)d_in[5];
    const float* db = (const float*)d_in[6];
    float* out = (float*)d_out;

    char* wsb = (char*)d_ws;
    const size_t MB = 1u << 20;
    short* qh    = (short*)(wsb + 0 * MB);
    short* ql    = (short*)(wsb + 1 * MB);
    short* kh    = (short*)(wsb + 2 * MB);
    short* kl    = (short*)(wsb + 3 * MB);
    float* vv    = (float*)(wsb + 4 * MB);   // 2 MB
    short* varr  = (short*)(wsb + 6 * MB);   // 2 MB
    float* part  = (float*)(wsb + 8 * MB);   // 16 MB
    float* coef  = (float*)(wsb + 24 * MB);  // 64 KB
    float* inter = (float*)(wsb + 25 * MB);  // 2 MB

    hipLaunchKernelGGL(k_embed, dim3(256), dim3(256), 0, stream,
                       x, cw, cb, pw, pb, qh, ql, kh, kl, vv, coef);
    hipLaunchKernelGGL(k_varr, dim3(512), dim3(256), 0, stream, vv, varr);
    hipLaunchKernelGGL(k_attn, dim3(1024), dim3(256), 0, stream,
                       qh, ql, kh, kl, varr, part);
    hipLaunchKernelGGL(k_reduce, dim3(512), dim3(256), 0, stream,
                       part, vv, coef, inter);
    hipLaunchKernelGGL(k_deconv, dim3(256), dim3(512), 0, stream,
                       inter, dw, db, out);
}